// Round 1
// baseline (584.205 us; speedup 1.0000x reference)
//
#include <hip/hip_runtime.h>

#define N     4096
#define FIN   256
#define CC    256   // HEADS * F_OUT
#define HEADS 4
#define FOUT  64
#define TI1   16    // i-rows per block, kernel 1
#define TI    16    // i-rows per block, kernel 2
#define CJ    64    // j-chunk

// Kernel 1: h = x @ W (4096x256 @ 256x256), plus e1[n,h] = <h[n,h,:], a1>,
// e2[n,h] = <h[n,h,:], a2> via wave reductions (wave == head).
__global__ __launch_bounds__(256) void gat_k1(const float* __restrict__ x,
                                              const float* __restrict__ W,
                                              const float* __restrict__ a,
                                              float* __restrict__ hmat,
                                              float* __restrict__ e1,
                                              float* __restrict__ e2) {
    __shared__ __align__(16) float xs[TI1 * FIN];   // 16 KB, contiguous x tile
    const int t  = threadIdx.x;
    const int i0 = blockIdx.x * TI1;
    {
        const float4* src = (const float4*)(x + i0 * FIN);
        float4* dst = (float4*)xs;
        #pragma unroll
        for (int idx = 0; idx < (TI1 * FIN / 4) / 256; ++idx)
            dst[idx * 256 + t] = src[idx * 256 + t];
    }
    __syncthreads();

    float acc[TI1];
    #pragma unroll
    for (int i = 0; i < TI1; ++i) acc[i] = 0.f;

    for (int k = 0; k < FIN; k += 4) {
        const float w0 = W[(k + 0) * CC + t];
        const float w1 = W[(k + 1) * CC + t];
        const float w2 = W[(k + 2) * CC + t];
        const float w3 = W[(k + 3) * CC + t];
        #pragma unroll
        for (int i = 0; i < TI1; ++i) {
            const float4 xv = *(const float4*)&xs[i * FIN + k];  // LDS broadcast
            acc[i] = fmaf(xv.x, w0, acc[i]);
            acc[i] = fmaf(xv.y, w1, acc[i]);
            acc[i] = fmaf(xv.z, w2, acc[i]);
            acc[i] = fmaf(xv.w, w3, acc[i]);
        }
    }

    #pragma unroll
    for (int i = 0; i < TI1; ++i) hmat[(i0 + i) * CC + t] = acc[i];

    // e1/e2: wave = head (t>>6), lane = f
    const int f  = t & 63;
    const int hd = t >> 6;
    const float a1 = a[f];
    const float a2 = a[FOUT + f];
    #pragma unroll
    for (int i = 0; i < TI1; ++i) {
        float s1 = acc[i] * a1;
        float s2 = acc[i] * a2;
        for (int m = 32; m > 0; m >>= 1) {
            s1 += __shfl_xor(s1, m, 64);
            s2 += __shfl_xor(s2, m, 64);
        }
        if (f == 0) {
            e1[(i0 + i) * HEADS + hd] = s1;
            e2[(i0 + i) * HEADS + hd] = s2;
        }
    }
}

// Kernel 2: masked-softmax aggregation. Block = 512 threads = 8 waves
// = 4 heads x 2 j-stripes. Each wave independently: generates its own
// 16x64 weight tile in LDS (lane = j), then consumes it broadcast
// (lane = f). Intra-wave dependency only -> no barriers in main loop.
__global__ __launch_bounds__(512) void gat_k2(const float* __restrict__ hmat,
                                              const int* __restrict__ adj,
                                              const float* __restrict__ e1g,
                                              const float* __restrict__ e2g,
                                              float* __restrict__ out) {
    __shared__ __align__(16) float wbuf[2][HEADS][TI][CJ];  // 32 KB
    __shared__ float zbuf[2][HEADS][TI];
    const int t    = threadIdx.x;
    const int g    = t >> 8;        // j-stripe 0/1
    const int lane = t & 63;
    const int hd   = (t >> 6) & 3;  // head
    const int i0   = blockIdx.x * TI;
    float* wslot = &wbuf[g][hd][0][0];

    float e1r[TI];
    #pragma unroll
    for (int i = 0; i < TI; ++i) e1r[i] = e1g[(i0 + i) * HEADS + hd];

    float acc[TI], zp[TI];
    #pragma unroll
    for (int i = 0; i < TI; ++i) { acc[i] = 0.f; zp[i] = 0.f; }

    for (int j0 = g * CJ; j0 < N; j0 += 2 * CJ) {
        // --- weight generation: lane = j ---
        const float e2v = e2g[(j0 + lane) * HEADS + hd];
        #pragma unroll
        for (int i = 0; i < TI; ++i) {
            const int av = adj[(i0 + i) * N + j0 + lane];
            float ev = e1r[i] + e2v;
            ev = ev > 0.f ? ev : 0.2f * ev;            // leaky relu
            const float wv = (av != 0) ? __expf(ev) : 0.f;
            wslot[i * CJ + lane] = wv;
            zp[i] += wv;
        }
        __builtin_amdgcn_wave_barrier();  // pin LDS write->read order

        // --- accumulation: lane = f; w reads are wave-uniform broadcasts ---
        const float* hrow = hmat + j0 * CC + (hd << 6) + lane;
        #pragma unroll 4
        for (int jg = 0; jg < CJ; jg += 4) {
            const float h0 = hrow[(jg + 0) * CC];
            const float h1 = hrow[(jg + 1) * CC];
            const float h2 = hrow[(jg + 2) * CC];
            const float h3 = hrow[(jg + 3) * CC];
            #pragma unroll
            for (int i = 0; i < TI; ++i) {
                const float4 wv = *(const float4*)&wslot[i * CJ + jg];
                acc[i] = fmaf(wv.x, h0, acc[i]);
                acc[i] = fmaf(wv.y, h1, acc[i]);
                acc[i] = fmaf(wv.z, h2, acc[i]);
                acc[i] = fmaf(wv.w, h3, acc[i]);
            }
        }
        __builtin_amdgcn_wave_barrier();
    }

    // --- epilogue: reduce Z across lanes, combine stripes + head mean ---
    #pragma unroll
    for (int i = 0; i < TI; ++i) {
        float z = zp[i];
        for (int m = 32; m > 0; m >>= 1) z += __shfl_xor(z, m, 64);
        zp[i] = z;
    }
    #pragma unroll
    for (int i = 0; i < TI; ++i) wslot[i * CJ + lane] = acc[i];  // reuse as [g][hd][i][f]
    if (lane == 0) {
        #pragma unroll
        for (int i = 0; i < TI; ++i) zbuf[g][hd][i] = zp[i];
    }
    __syncthreads();

    const int ib = t >> 6;  // 0..7
    #pragma unroll
    for (int rep = 0; rep < 2; ++rep) {
        const int ii = ib + rep * 8;
        float s = 0.f;
        #pragma unroll
        for (int hh = 0; hh < HEADS; ++hh) {
            const float num = wbuf[0][hh][ii][lane] + wbuf[1][hh][ii][lane];
            const float den = zbuf[0][hh][ii] + zbuf[1][hh][ii];
            s += num / den;
        }
        out[(i0 + ii) * FOUT + lane] = 0.25f * s;
    }
}

extern "C" void kernel_launch(void* const* d_in, const int* in_sizes, int n_in,
                              void* d_out, int out_size, void* d_ws, size_t ws_size,
                              hipStream_t stream) {
    const float* x   = (const float*)d_in[0];
    const int*   adj = (const int*)d_in[1];
    const float* W   = (const float*)d_in[2];
    const float* a   = (const float*)d_in[3];
    float* out  = (float*)d_out;
    float* hmat = (float*)d_ws;            // 4096*256 floats = 4 MB
    float* e1   = hmat + N * CC;           // 4096*4
    float* e2   = e1 + N * HEADS;          // 4096*4

    gat_k1<<<N / TI1, 256, 0, stream>>>(x, W, a, hmat, e1, e2);
    gat_k2<<<N / TI, 512, 0, stream>>>(hmat, adj, e1, e2, out);
}

// Round 2
// 210.852 us; speedup vs baseline: 2.7707x; 2.7707x over previous
//
#include <hip/hip_runtime.h>

#define N     4096
#define FIN   256
#define CC    256   // HEADS * F_OUT
#define HEADS 4
#define FOUT  64
#define TI1   8     // i-rows per block, kernel 1

typedef __attribute__((ext_vector_type(8))) short bf16x8;
typedef __attribute__((ext_vector_type(4))) float f32x4;

// float -> bf16 (round-nearest-even); w,h are finite, no NaN handling needed
__device__ inline short f2bf(float f) {
    unsigned u = __builtin_bit_cast(unsigned, f);
    unsigned r = u + 0x7fffu + ((u >> 16) & 1u);
    return (short)(r >> 16);
}

// Kernel 1: h = x @ W; writes hT[head][f][n] (bf16, transposed for k2's
// B-fragments) and e1T/e2T[head][n] via wave reductions (wave == head).
__global__ __launch_bounds__(256) void gat_k1(const float* __restrict__ x,
                                              const float* __restrict__ W,
                                              const float* __restrict__ a,
                                              short* __restrict__ hT,
                                              float* __restrict__ e1T,
                                              float* __restrict__ e2T) {
    __shared__ __align__(16) float xs[TI1 * FIN];   // 8 KB
    const int t  = threadIdx.x;
    const int i0 = blockIdx.x * TI1;
    {
        const float4* src = (const float4*)(x + i0 * FIN);
        float4* dst = (float4*)xs;
        #pragma unroll
        for (int idx = 0; idx < (TI1 * FIN / 4) / 256; ++idx)
            dst[idx * 256 + t] = src[idx * 256 + t];
    }
    __syncthreads();

    float acc[TI1];
    #pragma unroll
    for (int i = 0; i < TI1; ++i) acc[i] = 0.f;

    for (int k = 0; k < FIN; k += 4) {
        const float w0 = W[(k + 0) * CC + t];
        const float w1 = W[(k + 1) * CC + t];
        const float w2 = W[(k + 2) * CC + t];
        const float w3 = W[(k + 3) * CC + t];
        #pragma unroll
        for (int i = 0; i < TI1; ++i) {
            const float4 xv = *(const float4*)&xs[i * FIN + k];  // LDS broadcast
            acc[i] = fmaf(xv.x, w0, acc[i]);
            acc[i] = fmaf(xv.y, w1, acc[i]);
            acc[i] = fmaf(xv.z, w2, acc[i]);
            acc[i] = fmaf(xv.w, w3, acc[i]);
        }
    }

    const int f  = t & 63;
    const int hd = t >> 6;

    // hT[hd][f][i0..i0+7] <- acc, packed bf16, one 16B store per thread
    bf16x8 hv;
    #pragma unroll
    for (int i = 0; i < TI1; ++i) hv[i] = f2bf(acc[i]);
    *reinterpret_cast<bf16x8*>(hT + ((size_t)(hd * FOUT + f)) * N + i0) = hv;

    // e1/e2 wave reductions: lane = f
    const float a1 = a[f];
    const float a2 = a[FOUT + f];
    #pragma unroll
    for (int i = 0; i < TI1; ++i) {
        float s1 = acc[i] * a1;
        float s2 = acc[i] * a2;
        for (int m = 32; m > 0; m >>= 1) {
            s1 += __shfl_xor(s1, m, 64);
            s2 += __shfl_xor(s2, m, 64);
        }
        if (f == 0) {
            e1T[hd * N + i0 + i] = s1;
            e2T[hd * N + i0 + i] = s2;
        }
    }
}

// Kernel 2: masked-softmax aggregation via MFMA.
// grid 512 = 256 i-tiles x 2 head-groups (hb = bid>>8 so pair blocks share
// adj in L2). Block = 8 waves = 2 heads x 4 j-stripes. Each wave builds its
// attention A-fragment (16x32, bf16) IN REGISTERS (lane layout matches
// A[m=lane&15][k=quad*8+jj]), loads 4 h B-fragments from hT, and does 4
// mfma_f32_16x16x32_bf16 per 32-j step. No LDS, no barriers in main loop.
__global__ __launch_bounds__(512, 4) void gat_k2(const short* __restrict__ hT,
                                                 const int* __restrict__ adj,
                                                 const float* __restrict__ e1T,
                                                 const float* __restrict__ e2T,
                                                 float* __restrict__ out) {
    __shared__ float obuf[2][16][64];   // numerator accum, 8 KB
    __shared__ float zbuf[2][4][16];    // per-stripe Z partials
    const int t    = threadIdx.x;
    const int lane = t & 63;
    const int w    = t >> 6;        // wave 0..7
    const int hdl  = w & 1;         // head-local 0/1
    const int g    = w >> 1;        // j-stripe 0..3
    const int hb   = blockIdx.x >> 8;
    const int it   = blockIdx.x & 255;
    const int hd   = hb * 2 + hdl;
    const int i0   = it * 16;
    const int m    = lane & 15;     // MFMA row (i)
    const int q    = lane >> 4;     // quad -> k-subrange

    // zero the numerator buffer
    {
        float* ob = &obuf[0][0][0];
        #pragma unroll
        for (int r = 0; r < 4; ++r) ob[t + r * 512] = 0.f;
    }
    __syncthreads();

    const float e1v = e1T[hd * N + i0 + m];

    f32x4 accf[4];
    #pragma unroll
    for (int ft = 0; ft < 4; ++ft) accf[ft] = (f32x4){0.f, 0.f, 0.f, 0.f};
    float zacc = 0.f;

    const int* arow = adj + (size_t)(i0 + m) * N;
    const float* e2row = e2T + hd * N;
    const short* hrow = hT + (size_t)(hd * FOUT + m) * N;  // + ft*16*N per tile

    // prefetch step 0
    int jb = g * 32 + q * 8;
    int4 ca0 = *(const int4*)(arow + jb);
    int4 ca1 = *(const int4*)(arow + jb + 4);
    float4 ce0 = *(const float4*)(e2row + jb);
    float4 ce1 = *(const float4*)(e2row + jb + 4);

    for (int step = 0; step < 32; ++step) {
        const int jbase = g * 32 + step * 128 + q * 8;
        // prefetch next step's adj + e2
        int4 na0, na1; float4 ne0, ne1;
        if (step < 31) {
            const int jn = jbase + 128;
            na0 = *(const int4*)(arow + jn);
            na1 = *(const int4*)(arow + jn + 4);
            ne0 = *(const float4*)(e2row + jn);
            ne1 = *(const float4*)(e2row + jn + 4);
        }
        // B fragments: h[k=jbase+jj][f] from hT (8 contiguous bf16 each)
        bf16x8 bfrag[4];
        #pragma unroll
        for (int ft = 0; ft < 4; ++ft)
            bfrag[ft] = *reinterpret_cast<const bf16x8*>(hrow + (size_t)(ft * 16) * N + jbase);

        // generate 8 attention weights (lane covers k = q*8 .. q*8+7)
        const int   av[8] = {ca0.x, ca0.y, ca0.z, ca0.w, ca1.x, ca1.y, ca1.z, ca1.w};
        const float ev[8] = {ce0.x, ce0.y, ce0.z, ce0.w, ce1.x, ce1.y, ce1.z, ce1.w};
        bf16x8 afrag;
        #pragma unroll
        for (int jj = 0; jj < 8; ++jj) {
            float e = e1v + ev[jj];
            e = fmaxf(e, 0.2f * e);                 // leaky relu
            const float wv = (av[jj] != 0) ? __expf(e) : 0.f;
            zacc += wv;
            afrag[jj] = f2bf(wv);
        }

        #pragma unroll
        for (int ft = 0; ft < 4; ++ft)
            accf[ft] = __builtin_amdgcn_mfma_f32_16x16x32_bf16(afrag, bfrag[ft], accf[ft], 0, 0, 0);

        ca0 = na0; ca1 = na1; ce0 = ne0; ce1 = ne1;
    }

    // Z: sum over quads -> every lane holds Z for its row m (stripe-partial)
    zacc += __shfl_xor(zacc, 16, 64);
    zacc += __shfl_xor(zacc, 32, 64);
    if (lane < 16) zbuf[hdl][g][lane] = zacc;

    // numerator: C layout row=(lane>>4)*4+r, col=lane&15
    #pragma unroll
    for (int ft = 0; ft < 4; ++ft)
        #pragma unroll
        for (int r = 0; r < 4; ++r)
            atomicAdd(&obuf[hdl][q * 4 + r][ft * 16 + m], accf[ft][r]);
    __syncthreads();

    // combine: out[i][f] += 0.25 * num / Z   (2 head-group blocks per i-tile)
    #pragma unroll
    for (int rep = 0; rep < 4; ++rep) {
        const int idx = t + rep * 512;       // 0..2047
        const int hl  = idx >> 10;
        const int ii  = (idx >> 6) & 15;
        const int ff  = idx & 63;
        const float Z = zbuf[hl][0][ii] + zbuf[hl][1][ii] + zbuf[hl][2][ii] + zbuf[hl][3][ii];
        atomicAdd(&out[(size_t)(i0 + ii) * FOUT + ff], 0.25f * obuf[hl][ii][ff] / Z);
    }
}

extern "C" void kernel_launch(void* const* d_in, const int* in_sizes, int n_in,
                              void* d_out, int out_size, void* d_ws, size_t ws_size,
                              hipStream_t stream) {
    const float* x   = (const float*)d_in[0];
    const int*   adj = (const int*)d_in[1];
    const float* W   = (const float*)d_in[2];
    const float* a   = (const float*)d_in[3];
    float* out = (float*)d_out;

    short* hT  = (short*)d_ws;                       // 4*64*4096 bf16 = 2 MB
    float* e1T = (float*)(hT + (size_t)HEADS * FOUT * N);
    float* e2T = e1T + (size_t)HEADS * N;

    hipMemsetAsync(d_out, 0, (size_t)out_size * sizeof(float), stream);
    gat_k1<<<N / TI1, 256, 0, stream>>>(x, W, a, hT, e1T, e2T);
    gat_k2<<<512, 512, 0, stream>>>(hT, adj, e1T, e2T, out);
}

// Round 3
// 199.927 us; speedup vs baseline: 2.9221x; 1.0546x over previous
//
#include <hip/hip_runtime.h>

#define N     4096
#define FIN   256
#define CC    256   // HEADS * F_OUT
#define HEADS 4
#define FOUT  64

typedef __attribute__((ext_vector_type(8))) short bf16x8;
typedef __attribute__((ext_vector_type(4))) float f32x4;

// float -> bf16 (round-nearest-even)
__device__ inline short f2bf(float f) {
    unsigned u = __builtin_bit_cast(unsigned, f);
    unsigned r = u + 0x7fffu + ((u >> 16) & 1u);
    return (short)(r >> 16);
}

// Kernel 0: convert x (fp32) -> xb (bf16), coalesced.
__global__ __launch_bounds__(256) void gat_k0(const float* __restrict__ x,
                                              short* __restrict__ xb) {
    const int idx = blockIdx.x * 256 + threadIdx.x;   // over N*FIN/4
    const float4 v = ((const float4*)x)[idx];
    short4 o;
    o.x = f2bf(v.x); o.y = f2bf(v.y); o.z = f2bf(v.z); o.w = f2bf(v.w);
    ((short4*)xb)[idx] = o;
}

// Kernel 1: h = x @ W via MFMA (bf16 in, fp32 acc). One block = 64 n-rows x
// one head (64 c-cols). W column-slice staged transposed in LDS (bf16), A
// fragments straight from xb (contiguous). Outputs: hT[head][f][n] (bf16,
// j-contiguous for k2's B-frags), e1T/e2T[head][n] (fp32, from fp32 acc).
#define K1PAD 8
__global__ __launch_bounds__(256) void gat_k1(const short* __restrict__ xb,
                                              const float* __restrict__ W,
                                              const float* __restrict__ a,
                                              short* __restrict__ hT,
                                              float* __restrict__ e1T,
                                              float* __restrict__ e2T) {
    __shared__ __align__(16) short wts[64][FIN + K1PAD];   // W^T slice, 33.8 KB
    __shared__ __align__(16) short hbuf[64][64 + 8];       // transpose buf, 9 KB
    const int t  = threadIdx.x;
    const int hd = blockIdx.x >> 6;
    const int n0 = (blockIdx.x & 63) * 64;
    const int c0 = hd * 64;

    // stage W^T: thread t -> col c = t&63, k-rows (t>>6)*4 + 16*it
    {
        const int c  = t & 63;
        const int k4 = (t >> 6) * 4;
        #pragma unroll
        for (int it = 0; it < 16; ++it) {
            const int k = it * 16 + k4;
            short4 pk;
            pk.x = f2bf(W[(k + 0) * CC + c0 + c]);
            pk.y = f2bf(W[(k + 1) * CC + c0 + c]);
            pk.z = f2bf(W[(k + 2) * CC + c0 + c]);
            pk.w = f2bf(W[(k + 3) * CC + c0 + c]);
            *(short4*)&wts[c][k] = pk;
        }
    }
    __syncthreads();

    const int lane = t & 63;
    const int w    = t >> 6;       // wave -> n-strip
    const int m    = lane & 15;
    const int q    = lane >> 4;
    const int nrow = n0 + w * 16 + m;

    f32x4 acc[4];
    #pragma unroll
    for (int ct = 0; ct < 4; ++ct) acc[ct] = (f32x4){0.f, 0.f, 0.f, 0.f};

    const short* arow = xb + (size_t)nrow * FIN + q * 8;
    #pragma unroll
    for (int ks = 0; ks < 8; ++ks) {
        const bf16x8 af = *(const bf16x8*)(arow + ks * 32);
        #pragma unroll
        for (int ct = 0; ct < 4; ++ct) {
            const bf16x8 bf_ = *(const bf16x8*)&wts[ct * 16 + m][ks * 32 + q * 8];
            acc[ct] = __builtin_amdgcn_mfma_f32_16x16x32_bf16(af, bf_, acc[ct], 0, 0, 0);
        }
    }

    // e1/e2 from fp32 acc: per-lane partial over ct, butterfly over m (16)
    const float a1v[4] = {a[m], a[16 + m], a[32 + m], a[48 + m]};
    const float a2v[4] = {a[64 + m], a[80 + m], a[96 + m], a[112 + m]};
    #pragma unroll
    for (int r = 0; r < 4; ++r) {
        float s1 = 0.f, s2 = 0.f;
        #pragma unroll
        for (int ct = 0; ct < 4; ++ct) {
            s1 = fmaf(acc[ct][r], a1v[ct], s1);
            s2 = fmaf(acc[ct][r], a2v[ct], s2);
        }
        #pragma unroll
        for (int sh = 1; sh < 16; sh <<= 1) {
            s1 += __shfl_xor(s1, sh, 64);
            s2 += __shfl_xor(s2, sh, 64);
        }
        if (m == 0) {
            const int n = n0 + w * 16 + q * 4 + r;
            e1T[hd * N + n] = s1;
            e2T[hd * N + n] = s2;
        }
    }

    // transpose to hT[c][n] via LDS
    #pragma unroll
    for (int ct = 0; ct < 4; ++ct)
        #pragma unroll
        for (int r = 0; r < 4; ++r)
            hbuf[ct * 16 + m][w * 16 + q * 4 + r] = f2bf(acc[ct][r]);
    __syncthreads();

    const int f  = t >> 2;
    const int nn = (t & 3) * 16;
    const bf16x8 h0 = *(const bf16x8*)&hbuf[f][nn];
    const bf16x8 h1 = *(const bf16x8*)&hbuf[f][nn + 8];
    short* dst = hT + (size_t)(hd * FOUT + f) * N + n0 + nn;
    *(bf16x8*)dst = h0;
    *(bf16x8*)(dst + 8) = h1;
}

// Kernel 2: masked-softmax aggregation via MFMA. One head per block; block =
// 8 waves = 8 j-stripes, so Z completes in-block. Grid 1024 = 4 blocks/CU ->
// 32 waves/CU (100% occupancy) for adj latency hiding. bid swizzled so the 4
// head-blocks of an i-tile land on one XCD (share adj in its L2).
__global__ __launch_bounds__(512, 8) void gat_k2(const short* __restrict__ hT,
                                                 const int* __restrict__ adj,
                                                 const float* __restrict__ e1T,
                                                 const float* __restrict__ e2T,
                                                 float* __restrict__ out) {
    __shared__ float obuf[16][64];   // numerator, 4 KB
    __shared__ float zbuf[8][16];
    const int t    = threadIdx.x;
    const int lane = t & 63;
    const int g    = t >> 6;                       // j-stripe 0..7
    const int bid  = blockIdx.x;
    const int hd   = (bid >> 3) & 3;
    const int it   = (bid & 7) | ((bid >> 5) << 3);   // XCD = it & 7
    const int i0   = it * 16;
    const int m    = lane & 15;
    const int q    = lane >> 4;

    {
        float* ob = &obuf[0][0];
        ob[t] = 0.f; ob[t + 512] = 0.f;
    }
    __syncthreads();

    const float e1v = e1T[hd * N + i0 + m];

    f32x4 accf[4];
    #pragma unroll
    for (int ft = 0; ft < 4; ++ft) accf[ft] = (f32x4){0.f, 0.f, 0.f, 0.f};
    float zacc = 0.f;

    const int*   arow  = adj + (size_t)(i0 + m) * N;
    const float* e2row = e2T + hd * N;
    const short* hrow  = hT + (size_t)(hd * FOUT + m) * N;

    // prefetch step 0
    const int jb0 = g * 32 + q * 8;
    int4 ca0 = *(const int4*)(arow + jb0);
    int4 ca1 = *(const int4*)(arow + jb0 + 4);
    float4 ce0 = *(const float4*)(e2row + jb0);
    float4 ce1 = *(const float4*)(e2row + jb0 + 4);

    for (int step = 0; step < 16; ++step) {
        const int jbase = g * 32 + step * 256 + q * 8;
        int4 na0, na1; float4 ne0, ne1;
        if (step < 15) {
            const int jn = jbase + 256;
            na0 = *(const int4*)(arow + jn);
            na1 = *(const int4*)(arow + jn + 4);
            ne0 = *(const float4*)(e2row + jn);
            ne1 = *(const float4*)(e2row + jn + 4);
        }
        bf16x8 bfrag[4];
        #pragma unroll
        for (int ft = 0; ft < 4; ++ft)
            bfrag[ft] = *(const bf16x8*)(hrow + (size_t)(ft * 16) * N + jbase);

        const int   av[8] = {ca0.x, ca0.y, ca0.z, ca0.w, ca1.x, ca1.y, ca1.z, ca1.w};
        const float ev[8] = {ce0.x, ce0.y, ce0.z, ce0.w, ce1.x, ce1.y, ce1.z, ce1.w};
        bf16x8 afrag;
        #pragma unroll
        for (int jj = 0; jj < 8; ++jj) {
            float e = e1v + ev[jj];
            e = fmaxf(e, 0.2f * e);
            const float wv = (av[jj] != 0) ? __expf(e) : 0.f;
            zacc += wv;
            afrag[jj] = f2bf(wv);
        }

        #pragma unroll
        for (int ft = 0; ft < 4; ++ft)
            accf[ft] = __builtin_amdgcn_mfma_f32_16x16x32_bf16(afrag, bfrag[ft], accf[ft], 0, 0, 0);

        ca0 = na0; ca1 = na1; ce0 = ne0; ce1 = ne1;
    }

    // Z: sum quads -> stripe partial per row m
    zacc += __shfl_xor(zacc, 16, 64);
    zacc += __shfl_xor(zacc, 32, 64);
    if (lane < 16) zbuf[g][lane] = zacc;

    // numerator: C layout row=q*4+r, col=ft*16+m
    #pragma unroll
    for (int ft = 0; ft < 4; ++ft)
        #pragma unroll
        for (int r = 0; r < 4; ++r)
            atomicAdd(&obuf[q * 4 + r][ft * 16 + m], accf[ft][r]);
    __syncthreads();

    #pragma unroll
    for (int rep = 0; rep < 2; ++rep) {
        const int idx = t + rep * 512;
        const int ii  = idx >> 6;
        const int ff  = idx & 63;
        float Z = 0.f;
        #pragma unroll
        for (int gg = 0; gg < 8; ++gg) Z += zbuf[gg][ii];
        atomicAdd(&out[(size_t)(i0 + ii) * FOUT + ff], 0.25f * obuf[ii][ff] / Z);
    }
}

extern "C" void kernel_launch(void* const* d_in, const int* in_sizes, int n_in,
                              void* d_out, int out_size, void* d_ws, size_t ws_size,
                              hipStream_t stream) {
    const float* x   = (const float*)d_in[0];
    const int*   adj = (const int*)d_in[1];
    const float* W   = (const float*)d_in[2];
    const float* a   = (const float*)d_in[3];
    float* out = (float*)d_out;

    short* xb  = (short*)d_ws;                          // 4096*256 bf16 = 2 MB
    short* hT  = xb + (size_t)N * FIN;                  // 2 MB
    float* e1T = (float*)(hT + (size_t)HEADS * FOUT * N);
    float* e2T = e1T + (size_t)HEADS * N;               // total ~4.2 MB

    gat_k0<<<(N * FIN / 4) / 256, 256, 0, stream>>>(x, xb);
    gat_k1<<<256, 256, 0, stream>>>(xb, W, a, hT, e1T, e2T);
    hipMemsetAsync(d_out, 0, (size_t)out_size * sizeof(float), stream);
    gat_k2<<<1024, 512, 0, stream>>>(hT, adj, e1T, e2T, out);
}